// Round 1
// baseline (236.707 us; speedup 1.0000x reference)
//
#include <hip/hip_runtime.h>

#define NPIX 16384
#define IMW  128
#define BIGL 0x7FFFFFFF

__device__ __forceinline__ int find_root(int* L, int a){
    int p = L[a];
    while(p != a){
        int gp = L[p];
        if(gp != p) L[a] = gp;   // path halving; benign race (writes valid ancestor)
        a = p; p = gp;
    }
    return a;
}

__device__ __forceinline__ void unite(int* L, int a, int b){
    while(true){
        a = find_root(L, a);
        b = find_root(L, b);
        if(a == b) return;
        int hi = (a > b) ? a : b;
        int lo = (a > b) ? b : a;
        int old = atomicCAS(&L[hi], hi, lo);
        if(old == hi) return;
        a = old; b = lo;
    }
}

// One block per (ch, threshold, region): binarize into LDS, union-find CCL,
// count roots (b0), pixels, 4-neighbor edges. betti[ch][t][r][2] = {b0, b1}.
__global__ __launch_bounds__(256) void ccl_kernel(const float* __restrict__ prob,
                                                  const int*   __restrict__ sel,
                                                  float*       __restrict__ betti){
    __shared__ int L[NPIX];   // 64 KB
    const int bid = blockIdx.x;
    const int ch  = bid / 400;
    const int t   = (bid % 400) >> 2;
    const int r   = bid & 3;
    const float th = (float)t / 99.0f;
    const int region = sel[r];
    const float* img = prob + ((size_t)(region * 3 + ch)) * NPIX;
    const int tid = threadIdx.x;

    for(int i = tid; i < NPIX; i += 256)
        L[i] = (img[i] > th) ? i : BIGL;
    __syncthreads();

    int pix = 0, edges = 0;
    for(int i = tid; i < NPIX; i += 256){
        if(L[i] == BIGL) continue;     // bg stays BIGL forever; fg labels stay <= 16383
        pix++;
        int x = i & (IMW - 1);
        if(x < IMW - 1 && L[i + 1]   != BIGL){ edges++; unite(L, i, i + 1);   }
        if(i < NPIX - IMW && L[i + IMW] != BIGL){ edges++; unite(L, i, i + IMW); }
    }
    __syncthreads();

    int b0 = 0;
    for(int i = tid; i < NPIX; i += 256) b0 += (L[i] == i) ? 1 : 0;

    // block reduce (4 waves of 64)
    for(int off = 32; off > 0; off >>= 1){
        pix   += __shfl_down(pix,   off, 64);
        edges += __shfl_down(edges, off, 64);
        b0    += __shfl_down(b0,    off, 64);
    }
    __syncthreads();                 // all reads of L done; safe to reuse
    const int wv = tid >> 6;
    if((tid & 63) == 0){ L[wv*3+0] = pix; L[wv*3+1] = edges; L[wv*3+2] = b0; }
    __syncthreads();
    if(tid == 0){
        int P = 0, E = 0, B = 0;
        for(int w = 0; w < 4; w++){ P += L[w*3]; E += L[w*3+1]; B += L[w*3+2]; }
        float b0f = (float)B;
        float b1f = b0f - ((float)P - (float)E);   // b1 = b0 - euler
        size_t o = (((size_t)ch*100 + t)*4 + r)*2;
        betti[o]     = b0f;
        betti[o + 1] = b1f;
    }
}

// One block per (region, code-column) row: diff codes across thresholds,
// birth/death, stable-partition sort (== stable argsort by birth), stable
// rank-sort of gt row, L1 match + unmatched length partial sums.
__global__ __launch_bounds__(128) void rows_kernel(const float* __restrict__ betti,
                                                   const float* __restrict__ gt,
                                                   float*       __restrict__ partials){
    __shared__ float codes[100];
    __shared__ float birth[99], death[99], bs0[99], bs1[99], gs0[99], gs1[99];
    __shared__ float red[4];
    const int row = blockIdx.x;          // r*6 + j
    const int r = row / 6, j = row % 6;
    // codes columns: [inside.b0, inside.b1, boundary.b0, boundary.b1, union(=inside).b0, union.b1]
    const int chmap[6] = {0, 0, 1, 1, 0, 0};
    const int ch = chmap[j], comp = j & 1;
    const int tid = threadIdx.x;

    if(tid < 100) codes[tid] = betti[(((size_t)ch*100 + tid)*4 + r)*2 + comp];
    __syncthreads();

    float b = 0.f, d = 0.f;
    if(tid < 99){
        float dv = codes[tid + 1] - codes[tid];
        float th = (float)tid / 99.0f;
        b = (dv > 0.f) ? th : 0.f;
        d = (dv < 0.f) ? th : 0.f;
        birth[tid] = b; death[tid] = d;
    }
    __syncthreads();

    const float* g = gt + (size_t)row * 99 * 2;
    if(tid < 99){
        // stable sort by birth == stable partition: zero-births (t-order), then
        // positive births (t-order; strictly increasing so already sorted).
        int zb = 0, tz = 0;
        for(int k = 0; k < 99; k++){
            int z = (birth[k] == 0.f) ? 1 : 0;
            tz += z;
            if(k < tid) zb += z;
        }
        int pos = (b == 0.f) ? zb : (tz + tid - zb);
        bs0[pos] = b; bs1[pos] = d;

        // gt: stable rank sort by g[...,0]
        float gb = g[tid*2];
        int rank = 0;
        for(int k = 0; k < 99; k++){
            float o = g[k*2];
            rank += (o < gb || (o == gb && k < tid)) ? 1 : 0;
        }
        gs0[rank] = gb; gs1[rank] = g[tid*2 + 1];
    }
    __syncthreads();

    float m = 0.f, u = 0.f;
    if(tid < 99){
        m = fabsf(bs0[tid] - gs0[tid]) + fabsf(bs1[tid] - gs1[tid]);
        u = d - b;
    }
    for(int off = 32; off > 0; off >>= 1){
        m += __shfl_down(m, off, 64);
        u += __shfl_down(u, off, 64);
    }
    if((tid & 63) == 0){ red[(tid >> 6)*2] = m; red[(tid >> 6)*2 + 1] = u; }
    __syncthreads();
    if(tid == 0){
        partials[row]      = red[0] + red[2];
        partials[24 + row] = red[1] + red[3];
    }
}

__global__ __launch_bounds__(64) void final_kernel(const float* __restrict__ partials,
                                                   float* __restrict__ out){
    const int tid = threadIdx.x;
    float m = (tid < 24) ? partials[tid]      : 0.f;
    float u = (tid < 24) ? partials[24 + tid] : 0.f;
    for(int off = 32; off > 0; off >>= 1){
        m += __shfl_down(m, off, 64);
        u += __shfl_down(u, off, 64);
    }
    if(tid == 0) out[0] = m / 2376.0f + u / 24.0f;   // mean over [4,6,99] + mean over [4,6]
}

extern "C" void kernel_launch(void* const* d_in, const int* in_sizes, int n_in,
                              void* d_out, int out_size, void* d_ws, size_t ws_size,
                              hipStream_t stream){
    const float* prob = (const float*)d_in[0];   // [4,3,128,128] f32
    const int*   sel  = (const int*)d_in[1];     // [4] int32 (x64 disabled -> int32)
    const float* gt   = (const float*)d_in[2];   // [4,6,99,2] f32
    float* ws       = (float*)d_ws;
    float* betti    = ws;            // [2][100][4][2] = 1600 floats
    float* partials = ws + 1600;     // matched[24] + unmatched[24]

    ccl_kernel  <<<800, 256, 0, stream>>>(prob, sel, betti);
    rows_kernel <<<24, 128, 0, stream>>>(betti, gt, partials);
    final_kernel<<<1, 64, 0, stream>>>(partials, (float*)d_out);
}